// Round 2
// 1436.916 us; speedup vs baseline: 1.7497x; 1.7497x over previous
//
#include <hip/hip_runtime.h>
#include <cstdint>
#include <cstddef>

#define B_ 4096
#define T_ 128
#define N_ 128
#define H_ 128
#define G4_ 512       // 4*H
#define KC_ 256       // concat K = [x|h]
#define EPS_ 1e-5f

#define RPB_ 16       // batch rows per block
#define NB_ 256       // blocks (one per CU)
#define W0K_ 128      // layer0 K-half staged in LDS (k = 0..127, the x-part)
#define W0P_ 136      // padded LDS stride for W0l (136*2B = 272B, 16B-aligned rows, bank-spread)

typedef _Float16 f16x8 __attribute__((ext_vector_type(8)));
typedef _Float16 f16x4 __attribute__((ext_vector_type(4)));
typedef float f32x4 __attribute__((ext_vector_type(4)));

__device__ __forceinline__ float sigm_(float x) { return 1.f / (1.f + __expf(-x)); }
__device__ __forceinline__ float tanh_(float x) {
  float ax = fabsf(x);
  float e = __expf(-2.f * ax);
  float t = (1.f - e) / (1.f + e);
  return copysignf(t, x);
}

// ---------------- K0: pack weights to f16 [2][512][256] = [Wih | Whh], combine biases, zero stats
__global__ void k0_prep(const float* __restrict__ Wih0, const float* __restrict__ Whh0,
                        const float* __restrict__ bih0, const float* __restrict__ bhh0,
                        const float* __restrict__ Wih1, const float* __restrict__ Whh1,
                        const float* __restrict__ bih1, const float* __restrict__ bhh1,
                        _Float16* __restrict__ Wpack, float* __restrict__ bpack,
                        float* __restrict__ sumb, float* __restrict__ sqb) {
  int idx = blockIdx.x * blockDim.x + threadIdx.x;
  if (idx < 2 * G4_ * KC_) {
    int k = idx & (KC_ - 1);
    int j = (idx >> 8) & (G4_ - 1);
    int l = idx >> 17;
    const float* Wih = l ? Wih1 : Wih0;
    const float* Whh = l ? Whh1 : Whh0;
    float v = (k < N_) ? Wih[j * N_ + k] : Whh[j * N_ + (k - N_)];
    Wpack[idx] = (_Float16)v;
  }
  if (idx < 2 * G4_) {
    int j = idx & (G4_ - 1);
    bpack[idx] = (idx >> 9) ? (bih1[j] + bhh1[j]) : (bih0[j] + bhh0[j]);
  }
  if (idx < T_ * N_) { sumb[idx] = 0.f; sqb[idx] = 0.f; }
}

// ---------------- K1: score_x + softmax over n -> alpha[b][n]  (time-invariant!)
__global__ void k1_alpha(const float* __restrict__ X, const float* __restrict__ attn_w,
                         const float* __restrict__ attn_b, float* __restrict__ alpha) {
  __shared__ float wx[T_];
  __shared__ float red[4];
  int b = blockIdx.x;
  int n = threadIdx.x;  // 0..127
  wx[n] = attn_w[2 * H_ + n];
  __syncthreads();
  const float* xp = X + (size_t)b * T_ * N_ + n;
  float s = 0.f;
#pragma unroll 8
  for (int t = 0; t < T_; ++t) s = fmaf(xp[t * N_], wx[t], s);
  s += attn_b[0];
  float m = s;
#pragma unroll
  for (int off = 32; off >= 1; off >>= 1) m = fmaxf(m, __shfl_xor(m, off));
  if ((n & 63) == 0) red[n >> 6] = m;
  __syncthreads();
  m = fmaxf(red[0], red[1]);
  float e = __expf(s - m);
  float sm = e;
#pragma unroll
  for (int off = 32; off >= 1; off >>= 1) sm += __shfl_xor(sm, off);
  if ((n & 63) == 0) red[2 + (n >> 6)] = sm;
  __syncthreads();
  sm = red[2] + red[3];
  alpha[b * N_ + n] = e / sm;
}

// ---------------- K2: X_tilde = alpha*X (write output 0) + BN partial stats per (t,n)
__global__ void k2_xtilde(const float* __restrict__ X, const float* __restrict__ alpha,
                          float* __restrict__ out0, float* __restrict__ sumb,
                          float* __restrict__ sqb) {
  int t = blockIdx.x;
  int chunk = blockIdx.y;
  int n = threadIdx.x & (N_ - 1);
  int bi = threadIdx.x >> 7;  // 0/1
  float s = 0.f, q = 0.f;
  for (int it = 0; it < 128; ++it) {
    int b = (chunk << 8) + (it << 1) + bi;
    float a = alpha[b * N_ + n];
    size_t off = ((size_t)b * T_ + t) * N_ + n;
    float v = a * X[off];
    out0[off] = v;
    s += v;
    q += v * v;
  }
  __shared__ float ps[2][N_], pq[2][N_];
  ps[bi][n] = s;
  pq[bi][n] = q;
  __syncthreads();
  if (bi == 0) {
    atomicAdd(&sumb[t * N_ + n], ps[0][n] + ps[1][n]);
    atomicAdd(&sqb[t * N_ + n], pq[0][n] + pq[1][n]);
  }
}

// ---------------- K3: finalize BN -> per-(t,n) scale/shift
__global__ void k3_finalize(const float* __restrict__ sumb, const float* __restrict__ sqb,
                            const float* __restrict__ gamma, const float* __restrict__ beta,
                            float* __restrict__ scale, float* __restrict__ shift) {
  int i = blockIdx.x * blockDim.x + threadIdx.x;
  if (i >= T_ * N_) return;
  int n = i & (N_ - 1);
  float mean = sumb[i] * (1.f / B_);
  float var = sqb[i] * (1.f / B_) - mean * mean;
  float rstd = rsqrtf(var + EPS_);
  float g = gamma[n];
  scale[i] = rstd * g;
  shift[i] = beta[n] - mean * rstd * g;
}

// ---------------- K4: 2-layer LSTM recurrence, v2.
// 256 blocks x 16 rows, 8 waves/block. Wave w owns output cols [w*16, w*16+16) and
// computes ALL FOUR gates for them -> activation is register-only (no gate LDS exchange).
// Layer-1 weights live in 128 VGPRs/wave. Layer-0 k=0..127 lives in LDS; k=128..255
// streamed from L2 each step.
__global__ __launch_bounds__(512, 2) void k4_recur(
    const float* __restrict__ xt /* X_tilde */, const _Float16* __restrict__ Wpack,
    const float* __restrict__ bpack, const float* __restrict__ scale,
    const float* __restrict__ shift, float* __restrict__ out1) {
  __shared__ _Float16 W0l[G4_][W0P_];  // 139264 B
  __shared__ _Float16 A0[RPB_][264];   // [xb | h0], 8448 B
  __shared__ _Float16 A1[RPB_][264];   // [h0n | h1], 8448 B   (total 156160 B < 160 KiB)

  const int tid = threadIdx.x;
  const int w = tid >> 6;           // wave 0..7
  const int lane = tid & 63;
  const int quad = lane >> 4;
  const int l16 = lane & 15;
  const int nb = blockIdx.x;
  const int col = (w << 4) + l16;   // output col 0..127 owned by this lane

  // ---- one-time: stage layer0 K-half (x-part) into LDS. Thread t copies row t.
  {
    const _Float16* src = Wpack + (size_t)tid * KC_;
#pragma unroll
    for (int kk = 0; kk < W0K_; kk += 8)
      *(f16x8*)&W0l[tid][kk] = *(const f16x8*)&src[kk];
  }

  // ---- layer-1 weights resident in registers: 4 gates x 8 k-blocks x f16x8 = 128 VGPR
  f16x8 w1[4][8];
#pragma unroll
  for (int g = 0; g < 4; ++g) {
    const _Float16* src = Wpack + (size_t)(G4_ + (g << 7) + col) * KC_ + (quad << 3);
#pragma unroll
    for (int kb = 0; kb < 8; ++kb) w1[g][kb] = *(const f16x8*)&src[kb << 5];
  }

  float bia0[4], bia1[4];
#pragma unroll
  for (int g = 0; g < 4; ++g) {
    bia0[g] = bpack[(g << 7) + col];
    bia1[g] = bpack[G4_ + (g << 7) + col];
  }

  float c0[4], c1[4];
#pragma unroll
  for (int e = 0; e < 4; ++e) { c0[e] = 0.f; c1[e] = 0.f; }

  // staging coords: each thread stages 4 floats of one row
  const int srow = tid >> 5;          // 0..15
  const int scol = (tid & 31) << 2;   // 0..124
  const size_t browbase = (size_t)(nb * RPB_ + srow) * T_;

  // prologue: zero h-halves, stage xb(0)
  {
    f32x4 xv = *(const f32x4*)(xt + (browbase + 0) * N_ + scol);
    f32x4 sc = *(const f32x4*)(scale + scol);
    f32x4 sh = *(const f32x4*)(shift + scol);
    f16x4 hv;
#pragma unroll
    for (int e = 0; e < 4; ++e) hv[e] = (_Float16)fmaf(xv[e], sc[e], sh[e]);
    *(f16x4*)&A0[srow][scol] = hv;
    f16x4 z = {};
    *(f16x4*)&A0[srow][N_ + scol] = z;
    *(f16x4*)&A1[srow][N_ + scol] = z;
  }
  __syncthreads();

  for (int t = 0; t < T_; ++t) {
    // prefetch x(t+1) early; consumed after barrier #3
    f32x4 xn = {};
    if (t + 1 < T_) xn = *(const f32x4*)(xt + (browbase + t + 1) * N_ + scol);

    // ---- GEMM0: gates0[16][col..] = [xb|h0] @ W0^T ; kb 0..3 from LDS, 4..7 from L2
    f32x4 acc[4] = {};
#pragma unroll
    for (int kb = 0; kb < 8; ++kb) {
      f16x8 a = *(const f16x8*)&A0[l16][(kb << 5) + (quad << 3)];
      if (kb < 4) {
#pragma unroll
        for (int g = 0; g < 4; ++g) {
          f16x8 bf = *(const f16x8*)&W0l[(g << 7) + col][(kb << 5) + (quad << 3)];
          acc[g] = __builtin_amdgcn_mfma_f32_16x16x32_f16(a, bf, acc[g], 0, 0, 0);
        }
      } else {
#pragma unroll
        for (int g = 0; g < 4; ++g) {
          f16x8 bf = *(const f16x8*)(Wpack + (size_t)((g << 7) + col) * KC_ +
                                     (kb << 5) + (quad << 3));
          acc[g] = __builtin_amdgcn_mfma_f32_16x16x32_f16(a, bf, acc[g], 0, 0, 0);
        }
      }
    }

    // ---- act0 (register-only; acc rows = quad*4+e, col = this lane's col)
    _Float16 h0h[4];
#pragma unroll
    for (int e = 0; e < 4; ++e) {
      float ig = acc[0][e] + bia0[0];
      float fg = acc[1][e] + bia0[1];
      float gg = acc[2][e] + bia0[2];
      float og = acc[3][e] + bia0[3];
      float cn = sigm_(fg) * c0[e] + sigm_(ig) * tanh_(gg);
      c0[e] = cn;
      h0h[e] = (_Float16)(sigm_(og) * tanh_(cn));
    }
    __syncthreads();  // #1: all GEMM0 reads of A0 complete
#pragma unroll
    for (int e = 0; e < 4; ++e) {
      A0[(quad << 2) + e][N_ + col] = h0h[e];  // h0 for next step's GEMM0
      A1[(quad << 2) + e][col] = h0h[e];       // h0 input for GEMM1 now
    }
    __syncthreads();  // #2: A1 low half ready

    // ---- GEMM1: gates1 = [h0n|h1] @ W1^T ; B entirely from registers
    f32x4 acc1[4] = {};
#pragma unroll
    for (int kb = 0; kb < 8; ++kb) {
      f16x8 a = *(const f16x8*)&A1[l16][(kb << 5) + (quad << 3)];
#pragma unroll
      for (int g = 0; g < 4; ++g)
        acc1[g] = __builtin_amdgcn_mfma_f32_16x16x32_f16(a, w1[g][kb], acc1[g], 0, 0, 0);
    }

    // ---- act1 + output store
    _Float16 h1h[4];
#pragma unroll
    for (int e = 0; e < 4; ++e) {
      float ig = acc1[0][e] + bia1[0];
      float fg = acc1[1][e] + bia1[1];
      float gg = acc1[2][e] + bia1[2];
      float og = acc1[3][e] + bia1[3];
      float cn = sigm_(fg) * c1[e] + sigm_(ig) * tanh_(gg);
      c1[e] = cn;
      float hn = sigm_(og) * tanh_(cn);
      h1h[e] = (_Float16)hn;
      out1[((size_t)(nb * RPB_ + (quad << 2) + e) * T_ + t) * H_ + col] = hn;
    }
    __syncthreads();  // #3: all GEMM1 reads of A1 complete
#pragma unroll
    for (int e = 0; e < 4; ++e)
      A1[(quad << 2) + e][N_ + col] = h1h[e];  // h1 for next step's GEMM1
    if (t + 1 < T_) {                          // xb(t+1) from prefetched regs
      f32x4 sc = *(const f32x4*)(scale + (t + 1) * N_ + scol);
      f32x4 sh = *(const f32x4*)(shift + (t + 1) * N_ + scol);
      f16x4 hv;
#pragma unroll
      for (int e = 0; e < 4; ++e) hv[e] = (_Float16)fmaf(xn[e], sc[e], sh[e]);
      *(f16x4*)&A0[srow][scol] = hv;
    }
    __syncthreads();  // #4: A0 ready for next step
  }
}

extern "C" void kernel_launch(void* const* d_in, const int* in_sizes, int n_in,
                              void* d_out, int out_size, void* d_ws, size_t ws_size,
                              hipStream_t stream) {
  const float* X = (const float*)d_in[0];
  const float* attnw = (const float*)d_in[1];
  const float* attnb = (const float*)d_in[2];
  const float* gamma = (const float*)d_in[3];
  const float* beta = (const float*)d_in[4];
  const float* Wih0 = (const float*)d_in[5];
  const float* Whh0 = (const float*)d_in[6];
  const float* bih0 = (const float*)d_in[7];
  const float* bhh0 = (const float*)d_in[8];
  const float* Wih1 = (const float*)d_in[9];
  const float* Whh1 = (const float*)d_in[10];
  const float* bih1 = (const float*)d_in[11];
  const float* bhh1 = (const float*)d_in[12];

  float* out0 = (float*)d_out;                    // X_tilde
  float* out1 = out0 + (size_t)B_ * T_ * N_;      // X_encoded

  float* ws = (float*)d_ws;
  float* alpha = ws;                              // B*N
  float* sumb = alpha + (size_t)B_ * N_;          // T*N
  float* sqb = sumb + T_ * N_;
  float* scale = sqb + T_ * N_;
  float* shift = scale + T_ * N_;
  float* bpack = shift + T_ * N_;                 // 2*512
  _Float16* Wpack = (_Float16*)(bpack + 2 * G4_); // 2*512*256 f16 (16B-aligned)

  k0_prep<<<1024, 256, 0, stream>>>(Wih0, Whh0, bih0, bhh0, Wih1, Whh1, bih1, bhh1,
                                    Wpack, bpack, sumb, sqb);
  k1_alpha<<<B_, 128, 0, stream>>>(X, attnw, attnb, alpha);
  k2_xtilde<<<dim3(T_, 16), 256, 0, stream>>>(X, alpha, out0, sumb, sqb);
  k3_finalize<<<64, 256, 0, stream>>>(sumb, sqb, gamma, beta, scale, shift);
  k4_recur<<<NB_, 512, 0, stream>>>(out0, Wpack, bpack, scale, shift, out1);
}